// Round 16
// baseline (181.457 us; speedup 1.0000x reference)
//
#include <hip/hip_runtime.h>
#include <stdint.h>
#include <stddef.h>

typedef __attribute__((ext_vector_type(8))) short bf16x8;
typedef __attribute__((ext_vector_type(4))) float f32x4;
typedef __attribute__((ext_vector_type(4))) int i32x4;

#define NH 128
#define NW 128
#define NC 64
#define NF 256
#define SLOT 16384                 // one x-row tile in LDS: [w=128][cb=8 x 16B], XOR-swizzled

__device__ __forceinline__ unsigned short f2b(float f) {
  union { float f; uint32_t u; } t; t.f = f;
  uint32_t u = t.u;
  return (unsigned short)((u + 0x7fffu + ((u >> 16) & 1u)) >> 16);
}

// prep: B table only (72 blocks, ~3 us). Per-wave fragment order (R8-verified):
//   u16 elem ((fi*9+s)*16 + cf*2 + kk)*512 + lane*8 + e
//     = kern[(s*64 + (kk*4+(lane>>4))*8 + e)*NF + fi*128 + cf*16 + (lane&15)]
__global__ void prep_bt(const float* __restrict__ kr, unsigned short* __restrict__ ws) {
  int t = blockIdx.x * 256 + threadIdx.x;   // [0, 18432)
  int lane = t & 63;
  int kk   = (t >> 6) & 1;
  int cf   = (t >> 7) & 7;
  int rest = t >> 10;          // fi*9 + s
  int s  = rest % 9;
  int fi = rest / 9;
  int l15 = lane & 15, l4 = lane >> 4;
  int col = fi * 128 + cf * 16 + l15;
  int k0  = s * 64 + (kk * 4 + l4) * 8;
  unsigned short* dst = ws + (size_t)t * 8;
  const float* src = kr + (size_t)k0 * NF + col;
  #pragma unroll
  for (int e = 0; e < 8; ++e) dst[e] = f2b(src[(size_t)e * NF]);
}

// conv: R15 structure (16 waves/CU, NT full-line stores, setprio, in-kernel
// cast staging) + DEPTH-2 B prefetch (triple buffer, 48 VGPR — fits the 128
// cap unlike R7's 96-VGPR attempt) + NON-TEMPORAL B loads (no L1 reuse:
// don't evict staging lines).
__global__ __launch_bounds__(512, 4)
void conv_main(const float* __restrict__ x, const unsigned short* __restrict__ bt,
               const float* __restrict__ bias, float* __restrict__ out)
{
  __shared__ __align__(16) char lds[3 * SLOT];   // 48 KB; epilogue reuses

  const int tid  = threadIdx.x;
  const int lane = tid & 63;
  const int l15  = lane & 15;
  const int l4   = lane >> 4;
  const int wid  = tid >> 6;
  const int wm   = wid >> 2;    // 2: w-half
  const int wn   = wid & 3;     // 4: F-eighth (32 cols of this fi half)

  // XCD-aware bijective swizzle: nwg=4096, 512 per XCD; fi-pairs adjacent,
  // consecutive mi on one XCD -> x rows L2-shared across 6 readers.
  int bid  = (int)blockIdx.x;
  int work = (bid & 7) * 512 + (bid >> 3);
  int mi = work >> 1;           // (b,h) flat
  int fi = work & 1;
  int bb = mi >> 7;
  int hh = mi & 127;
  int F0 = fi * 128;

  const char* bimg = (const char*)bt + (size_t)fi * 9 * 16384;
  const int boff = wn * 4096 + lane * 16;   // frag n at +n*2048, kk at +kk*1024

  bf16x8 breg[3][2][2];   // triple buffer = 48 VGPR; all-static indices

  // ---- prologue: B(0)->buf0, B(1)->buf1 (issue first, fly under staging) ----
  #pragma unroll
  for (int n = 0; n < 2; ++n)
    #pragma unroll
    for (int kk = 0; kk < 2; ++kk) {
      breg[0][n][kk] = __builtin_nontemporal_load(
          (const bf16x8*)(bimg + boff + n * 2048 + kk * 1024));
      breg[1][n][kk] = __builtin_nontemporal_load(
          (const bf16x8*)(bimg + 16384 + boff + n * 2048 + kk * 1024));
    }

  // ---- stage A rows h-1,h,h+1 -> slots 0..2 (cast in-kernel) ----
  #pragma unroll
  for (int i = 0; i < 6; ++i) {
    int idx = tid + i * 512;            // 3072 16B-blocks (3 rows)
    int cb = idx & 7;
    int w  = (idx >> 3) & 127;
    int r  = idx >> 10;                 // 0..2
    int xr = (hh + r + 127) & 127;
    const float* src = x + (((size_t)(bb * NH + xr) * NW + w) * NC + cb * 8);
    float4 a0 = *(const float4*)(src);
    float4 a1 = *(const float4*)(src + 4);
    union { unsigned short u[8]; i32x4 v; } p;
    p.u[0] = f2b(a0.x); p.u[1] = f2b(a0.y); p.u[2] = f2b(a0.z); p.u[3] = f2b(a0.w);
    p.u[4] = f2b(a1.x); p.u[5] = f2b(a1.y); p.u[6] = f2b(a1.z); p.u[7] = f2b(a1.w);
    *(i32x4*)(lds + (r * SLOT + w * 128 + ((cb ^ (w & 7)) << 4))) = p.v;
  }
  __syncthreads();    // A staged; read-only hereafter

  // compressed A-address LUT (R10-verified):
  //   addr(m,dwi) = slotb + ((trow[dwi] + m*2048) & 16383) + swz[dwi]
  //   kk=1 address = kk=0 address XOR 64
  int trow[3], swz[3];
  #pragma unroll
  for (int dwi = 0; dwi < 3; ++dwi) {
    int t = l15 + 1 - dwi;
    trow[dwi] = ((wm * 64 + t) & 127) * 128;
    swz[dwi]  = (l4 ^ (t & 7)) << 4;
  }

  f32x4 acc[4][2];   // 32 VGPR
  #pragma unroll
  for (int m = 0; m < 4; ++m)
    #pragma unroll
    for (int n = 0; n < 2; ++n)
      acc[m][n] = (f32x4){0.f, 0.f, 0.f, 0.f};

  #pragma unroll
  for (int s = 0; s < 9; ++s) {
    if (s < 7) {  // depth-2 prefetch: B(s+2) -> just-freed buffer (s+2)%3
      const char* bs = bimg + (size_t)(s + 2) * 16384 + boff;
      #pragma unroll
      for (int n = 0; n < 2; ++n)
        #pragma unroll
        for (int kk = 0; kk < 2; ++kk)
          breg[(s + 2) % 3][n][kk] = __builtin_nontemporal_load(
              (const bf16x8*)(bs + n * 2048 + kk * 1024));
    }
    const int dwi   = s / 3;                  // static
    const int slotb = (2 - (s % 3)) * SLOT;   // static
    #pragma unroll
    for (int kk = 0; kk < 2; ++kk) {
      bf16x8 af[4];
      #pragma unroll
      for (int m = 0; m < 4; ++m) {
        int addr = slotb + ((trow[dwi] + m * 2048) & 16383) + swz[dwi];
        af[m] = *(const bf16x8*)(lds + (addr ^ (kk << 6)));
      }
      __builtin_amdgcn_s_setprio(1);
      #pragma unroll
      for (int m = 0; m < 4; ++m)
        #pragma unroll
        for (int n = 0; n < 2; ++n)
          acc[m][n] = __builtin_amdgcn_mfma_f32_16x16x32_bf16(
              af[m], breg[s % 3][n][kk], acc[m][n], 0, 0, 0);
      __builtin_amdgcn_s_setprio(0);
    }
  }

  // ---- epilogue: bias + FULL-LINE NON-TEMPORAL stores via LDS transpose ----
  float bv[2];
  #pragma unroll
  for (int n = 0; n < 2; ++n) bv[n] = bias[F0 + wn * 32 + n * 16 + l15];

  __syncthreads();
  float* eb = (float*)lds;              // [64][132] padded f32 tile (33.8 KB)

  #pragma unroll
  for (int chunk = 0; chunk < 2; ++chunk) {
    if (wm == chunk) {                  // owning 4 waves deposit acc+bias
      #pragma unroll
      for (int m = 0; m < 4; ++m)
        #pragma unroll
        for (int jj = 0; jj < 4; ++jj) {
          int r = m * 16 + l4 * 4 + jj;               // 0..63 chunk-local
          #pragma unroll
          for (int n = 0; n < 2; ++n)
            eb[r * 132 + wn * 32 + n * 16 + l15] = acc[m][n][jj] + bv[n];
        }
    }
    __syncthreads();
    // all 8 waves: per instr 64 lanes x f32x4 = 1024B contiguous; NT
    size_t obase = ((size_t)mi * 128 + chunk * 64) * NF + F0;
    #pragma unroll
    for (int i = 0; i < 4; ++i) {
      int r = i * 16 + (tid >> 5);          // 0..63
      int c = (tid & 31) * 4;               // 0..124
      f32x4 v = *(const f32x4*)(eb + r * 132 + c);
      __builtin_nontemporal_store(v, (f32x4*)(out + obase + (size_t)r * NF + c));
    }
    if (chunk == 0) __syncthreads();    // before chunk 1 overwrites eb
  }
}

extern "C" void kernel_launch(void* const* d_in, const int* in_sizes, int n_in,
                              void* d_out, int out_size, void* d_ws, size_t ws_size,
                              hipStream_t stream) {
  const float* x    = (const float*)d_in[0];
  const float* kern = (const float*)d_in[1];
  const float* bias = (const float*)d_in[2];
  float* out = (float*)d_out;
  unsigned short* bt = (unsigned short*)d_ws;   // 294912 bytes

  prep_bt<<<dim3(72), dim3(256), 0, stream>>>(kern, bt);
  conv_main<<<dim3(4096), dim3(512), 0, stream>>>(x, bt, bias, out);
}

// Round 17
// 95.025 us; speedup vs baseline: 1.9096x; 1.9096x over previous
//
#include <hip/hip_runtime.h>
#include <stdint.h>
#include <stddef.h>

typedef __attribute__((ext_vector_type(8))) short bf16x8;
typedef __attribute__((ext_vector_type(4))) float f32x4;
typedef __attribute__((ext_vector_type(4))) int i32x4;

#define NH 128
#define NW 128
#define NC 64
#define NF 256
#define SLOT 16384                 // one x-row tile in LDS: [w=128][cb=8 x 16B], XOR-swizzled

__device__ __forceinline__ unsigned short f2b(float f) {
  union { float f; uint32_t u; } t; t.f = f;
  uint32_t u = t.u;
  return (unsigned short)((u + 0x7fffu + ((u >> 16) & 1u)) >> 16);
}

// prep: B table only (72 blocks, ~3 us). Per-wave fragment order (R8-verified):
//   u16 elem ((fi*9+s)*16 + cf*2 + kk)*512 + lane*8 + e
//     = kern[(s*64 + (kk*4+(lane>>4))*8 + e)*NF + fi*128 + cf*16 + (lane&15)]
__global__ void prep_bt(const float* __restrict__ kr, unsigned short* __restrict__ ws) {
  int t = blockIdx.x * 256 + threadIdx.x;   // [0, 18432)
  int lane = t & 63;
  int kk   = (t >> 6) & 1;
  int cf   = (t >> 7) & 7;
  int rest = t >> 10;          // fi*9 + s
  int s  = rest % 9;
  int fi = rest / 9;
  int l15 = lane & 15, l4 = lane >> 4;
  int col = fi * 128 + cf * 16 + l15;
  int k0  = s * 64 + (kk * 4 + l4) * 8;
  unsigned short* dst = ws + (size_t)t * 8;
  const float* src = kr + (size_t)k0 * NF + col;
  #pragma unroll
  for (int e = 0; e < 8; ++e) dst[e] = f2b(src[(size_t)e * NF]);
}

// conv: R10 structure (256 thr, 4 waves, wave tile 64w x 64F -> MFMA:ds_read
// = 4:1, half the LDS-pipe load of the 32F shape; 3 blocks/CU = 12 waves)
// + NT full-line stores (R14-verified) + setprio. B register double-buffer
// (NO nt loads — R16 showed nt on re-read data is catastrophic).
__global__ __launch_bounds__(256, 3)
void conv_main(const float* __restrict__ x, const unsigned short* __restrict__ bt,
               const float* __restrict__ bias, float* __restrict__ out)
{
  __shared__ __align__(16) char lds[3 * SLOT];   // 48 KB; epilogue reuses

  const int tid  = threadIdx.x;
  const int lane = tid & 63;
  const int l15  = lane & 15;
  const int l4   = lane >> 4;
  const int wid  = tid >> 6;
  const int wm   = wid >> 1;    // 2: w-half
  const int wn   = wid & 1;     // 2: F-half of this fi half (64 cols)

  // XCD-aware bijective swizzle: nwg=4096, 512 per XCD.
  int bid  = (int)blockIdx.x;
  int work = (bid & 7) * 512 + (bid >> 3);
  int mi = work >> 1;           // (b,h) flat
  int fi = work & 1;
  int bb = mi >> 7;
  int hh = mi & 127;
  int F0 = fi * 128;

  const char* bimg = (const char*)bt + (size_t)fi * 9 * 16384;
  const int boff = (wn * 4) * 2048 + lane * 16;

  bf16x8 breg[2][4][2];   // double buffer = 64 VGPR, all-static indices

  // ---- prologue: B(0) -> buf0 (issues first, flies under staging VALU) ----
  #pragma unroll
  for (int n = 0; n < 4; ++n)
    #pragma unroll
    for (int kk = 0; kk < 2; ++kk)
      breg[0][n][kk] = *(const bf16x8*)(bimg + boff + n * 2048 + kk * 1024);

  // ---- stage A rows h-1,h,h+1 -> slots 0..2 (cast in-kernel) ----
  #pragma unroll
  for (int i = 0; i < 12; ++i) {
    int idx = tid + i * 256;            // 3072 16B-blocks (3 rows)
    int cb = idx & 7;
    int w  = (idx >> 3) & 127;
    int r  = idx >> 10;                 // 0..2
    int xr = (hh + r + 127) & 127;
    const float* src = x + (((size_t)(bb * NH + xr) * NW + w) * NC + cb * 8);
    float4 a0 = *(const float4*)(src);
    float4 a1 = *(const float4*)(src + 4);
    union { unsigned short u[8]; i32x4 v; } p;
    p.u[0] = f2b(a0.x); p.u[1] = f2b(a0.y); p.u[2] = f2b(a0.z); p.u[3] = f2b(a0.w);
    p.u[4] = f2b(a1.x); p.u[5] = f2b(a1.y); p.u[6] = f2b(a1.z); p.u[7] = f2b(a1.w);
    *(i32x4*)(lds + (r * SLOT + w * 128 + ((cb ^ (w & 7)) << 4))) = p.v;
  }
  __syncthreads();    // A staged; read-only hereafter

  // compressed A-address LUT (R10-verified):
  //   addr(m,dwi) = slotb + ((trow[dwi] + m*2048) & 16383) + swz[dwi]
  //   kk=1 address = kk=0 address XOR 64
  int trow[3], swz[3];
  #pragma unroll
  for (int dwi = 0; dwi < 3; ++dwi) {
    int t = l15 + 1 - dwi;
    trow[dwi] = ((wm * 64 + t) & 127) * 128;
    swz[dwi]  = (l4 ^ (t & 7)) << 4;
  }

  f32x4 acc[4][4];   // 64 VGPR
  #pragma unroll
  for (int m = 0; m < 4; ++m)
    #pragma unroll
    for (int n = 0; n < 4; ++n)
      acc[m][n] = (f32x4){0.f, 0.f, 0.f, 0.f};

  #pragma unroll
  for (int s = 0; s < 9; ++s) {
    if (s < 8) {  // depth-1 B prefetch -> other buffer (plain cached loads)
      const char* bs = bimg + (size_t)(s + 1) * 16384 + boff;
      #pragma unroll
      for (int n = 0; n < 4; ++n)
        #pragma unroll
        for (int kk = 0; kk < 2; ++kk)
          breg[(s + 1) & 1][n][kk] = *(const bf16x8*)(bs + n * 2048 + kk * 1024);
    }
    const int dwi   = s / 3;                  // static
    const int slotb = (2 - (s % 3)) * SLOT;   // static
    #pragma unroll
    for (int kk = 0; kk < 2; ++kk) {
      bf16x8 af[4];
      #pragma unroll
      for (int m = 0; m < 4; ++m) {
        int addr = slotb + ((trow[dwi] + m * 2048) & 16383) + swz[dwi];
        af[m] = *(const bf16x8*)(lds + (addr ^ (kk << 6)));
      }
      __builtin_amdgcn_s_setprio(1);
      #pragma unroll
      for (int m = 0; m < 4; ++m)
        #pragma unroll
        for (int n = 0; n < 4; ++n)
          acc[m][n] = __builtin_amdgcn_mfma_f32_16x16x32_bf16(
              af[m], breg[s & 1][n][kk], acc[m][n], 0, 0, 0);
      __builtin_amdgcn_s_setprio(0);
    }
  }

  // ---- epilogue: bias + FULL-LINE NON-TEMPORAL stores via LDS transpose ----
  float bv[4];
  #pragma unroll
  for (int n = 0; n < 4; ++n) bv[n] = bias[F0 + wn * 64 + n * 16 + l15];

  __syncthreads();
  float* eb = (float*)lds;              // [64][132] padded f32 tile

  #pragma unroll
  for (int chunk = 0; chunk < 2; ++chunk) {
    if (wm == chunk) {                  // owning wave-pair deposits acc+bias
      #pragma unroll
      for (int m = 0; m < 4; ++m)
        #pragma unroll
        for (int jj = 0; jj < 4; ++jj) {
          int r = m * 16 + l4 * 4 + jj;
          #pragma unroll
          for (int n = 0; n < 4; ++n)
            eb[r * 132 + wn * 64 + n * 16 + l15] = acc[m][n][jj] + bv[n];
        }
    }
    __syncthreads();
    size_t obase = ((size_t)mi * 128 + chunk * 64) * NF + F0;
    #pragma unroll
    for (int i = 0; i < 8; ++i) {
      int r = i * 8 + wid * 2 + (lane >> 5);
      int c = (lane & 31) * 4;
      f32x4 v = *(const f32x4*)(eb + r * 132 + c);
      __builtin_nontemporal_store(v, (f32x4*)(out + obase + (size_t)r * NF + c));
    }
    if (chunk == 0) __syncthreads();
  }
}

extern "C" void kernel_launch(void* const* d_in, const int* in_sizes, int n_in,
                              void* d_out, int out_size, void* d_ws, size_t ws_size,
                              hipStream_t stream) {
  const float* x    = (const float*)d_in[0];
  const float* kern = (const float*)d_in[1];
  const float* bias = (const float*)d_in[2];
  float* out = (float*)d_out;
  unsigned short* bt = (unsigned short*)d_ws;   // 294912 bytes

  prep_bt<<<dim3(72), dim3(256), 0, stream>>>(kern, bt);
  conv_main<<<dim3(4096), dim3(256), 0, stream>>>(x, bt, bias, out);
}